// Round 8
// baseline (87.464 us; speedup 1.0000x reference)
//
#include <hip/hip_runtime.h>

#define NN 8192
#define DD 64

typedef short bf16x8 __attribute__((ext_vector_type(8)));
typedef float f32x4 __attribute__((ext_vector_type(4)));

__device__ __forceinline__ unsigned short f2bf(float f) {
    unsigned int u = __float_as_uint(f);
    unsigned int r = (u + 0x7FFFu + ((u >> 16) & 1u)) >> 16;
    return (unsigned short)r;
}

__device__ __forceinline__ float fsqrt(float x) {
#if __has_builtin(__builtin_amdgcn_sqrtf)
    return __builtin_amdgcn_sqrtf(x);
#else
    return sqrtf(x);
#endif
}

// ---- Setup: X fp32 -> bf16 (RNE) into ws, plus per-row squared norms ----
__global__ __launch_bounds__(256) void rips_setup(const float* __restrict__ X,
                                                  unsigned short* __restrict__ Xb,
                                                  float* __restrict__ norms) {
    const int t   = blockIdx.x * 256 + threadIdx.x;
    const int row = t >> 3;
    const int j   = t & 7;
    const float* p = X + (size_t)row * DD + j * 8;
    float4 lo = *(const float4*)p;
    float4 hi = *(const float4*)(p + 4);

    bf16x8 v;
    v[0] = (short)f2bf(lo.x); v[1] = (short)f2bf(lo.y);
    v[2] = (short)f2bf(lo.z); v[3] = (short)f2bf(lo.w);
    v[4] = (short)f2bf(hi.x); v[5] = (short)f2bf(hi.y);
    v[6] = (short)f2bf(hi.z); v[7] = (short)f2bf(hi.w);
    *(bf16x8*)(Xb + (size_t)row * DD + j * 8) = v;

    float acc = lo.x*lo.x + lo.y*lo.y + lo.z*lo.z + lo.w*lo.w
              + hi.x*hi.x + hi.y*hi.y + hi.z*hi.z + hi.w*hi.w;
    acc += __shfl_xor(acc, 1);
    acc += __shfl_xor(acc, 2);
    acc += __shfl_xor(acc, 4);
    if (j == 0) norms[row] = acc;
}

// ---- Main (H3): one block = one 16-row FULL-WIDTH stripe = 512KB of output,
// a single contiguous memory region written front-to-back (mimics the fill
// kernel's macro pattern). 512 blocks x 512 threads (8 waves). Wave w owns
// cols [w*1024, w*1024+1024), 8 chunks of 128 cols. Per chunk: 16 MFMA
// (same totals as before), epilogue stages 16x64 halves in LDS, streams
// 4 rows x 256B per store inst; each row's bytes advance strictly
// sequentially over the block's lifetime.
__global__ __launch_bounds__(512) void rips_stripe(const unsigned short* __restrict__ Xb,
                                                   const float* __restrict__ norms,
                                                   float* __restrict__ out) {
    const int rowBase = blockIdx.x * 16;     // 512 stripes
    const int tid  = threadIdx.x;
    const int lane = tid & 63;
    const int w    = tid >> 6;               // wave 0..7

    const int fr = lane & 15;                // B-frag row / output row
    const int kg = lane >> 4;                // k-group / output col quad

    __shared__ float stage[8][16 * 68];      // per-wave 16x64 slice, stride 68
    float* st = stage[w];

    // Hoisted row fragments (B operand) and row norm.
    const bf16x8 b0 = *(const bf16x8*)(Xb + (size_t)(rowBase + fr) * DD + 0  + kg * 8);
    const bf16x8 b1 = *(const bf16x8*)(Xb + (size_t)(rowBase + fr) * DD + 32 + kg * 8);
    const float rnv = norms[rowBase + fr];

    const int sr = lane >> 4;                // 0..3 store row-in-group
    const int sc = lane & 15;                // 0..15 store 16B col group

    for (int c = 0; c < 8; ++c) {
        const int colBase = w * 1024 + c * 128;
        const bool hasDiag = ((rowBase >> 7) == (colBase >> 7));

        f32x4 acc[8];
        #pragma unroll
        for (int n = 0; n < 8; ++n) acc[n] = (f32x4){0.f, 0.f, 0.f, 0.f};

        {
            bf16x8 a[8];
            #pragma unroll
            for (int n = 0; n < 8; ++n)
                a[n] = *(const bf16x8*)(Xb + (size_t)(colBase + n * 16 + fr) * DD + 0 + kg * 8);
            #pragma unroll
            for (int n = 0; n < 8; ++n)
                acc[n] = __builtin_amdgcn_mfma_f32_16x16x32_bf16(a[n], b0, acc[n], 0, 0, 0);
            #pragma unroll
            for (int n = 0; n < 8; ++n)
                a[n] = *(const bf16x8*)(Xb + (size_t)(colBase + n * 16 + fr) * DD + 32 + kg * 8);
            #pragma unroll
            for (int n = 0; n < 8; ++n)
                acc[n] = __builtin_amdgcn_mfma_f32_16x16x32_bf16(a[n], b1, acc[n], 0, 0, 0);
        }

        const int grow = rowBase + fr;
        #pragma unroll
        for (int h = 0; h < 2; ++h) {
            #pragma unroll
            for (int nn = 0; nn < 4; ++nn) {
                const int idx   = h * 4 + nn;
                const int gcol0 = colBase + idx * 16 + kg * 4;
                const float4 cnv = *(const float4*)(norms + gcol0);
                f32x4 o;
                o[0] = fsqrt(fmaxf(rnv + cnv.x - 2.0f * acc[idx][0], 0.0f));
                o[1] = fsqrt(fmaxf(rnv + cnv.y - 2.0f * acc[idx][1], 0.0f));
                o[2] = fsqrt(fmaxf(rnv + cnv.z - 2.0f * acc[idx][2], 0.0f));
                o[3] = fsqrt(fmaxf(rnv + cnv.w - 2.0f * acc[idx][3], 0.0f));
                if (hasDiag) {
                    if (grow == gcol0 + 0) o[0] = 0.0f;
                    if (grow == gcol0 + 1) o[1] = 0.0f;
                    if (grow == gcol0 + 2) o[2] = 0.0f;
                    if (grow == gcol0 + 3) o[3] = 0.0f;
                }
                *(f32x4*)&st[fr * 68 + nn * 16 + kg * 4] = o;
            }
            // Stream half-chunk: 4 insts, each 4 rows x 256B contiguous;
            // consecutive h/c iterations extend every row strictly forward.
            #pragma unroll
            for (int t = 0; t < 4; ++t) {
                const int R = t * 4 + sr;                  // 0..15
                f32x4 v = *(const f32x4*)&st[R * 68 + sc * 4];
                const int srow = rowBase + R;
                const int scol = colBase + h * 64 + sc * 4;
                *(f32x4*)(out + (size_t)srow * NN + scol) = v;
            }
        }
    }
}

// ---- Fallback (R1 kernel): used only if ws_size is too small ----
__global__ __launch_bounds__(256) void rips_fallback(const float* __restrict__ X,
                                                     float* __restrict__ out) {
    const int rowBase = blockIdx.y * 128;
    const int colBase = blockIdx.x * 128;
    const int tid  = threadIdx.x;
    const int lane = tid & 63;
    const int w    = tid >> 6;
    const int wr   = w >> 1;
    const int wc   = w & 1;

    __shared__ float rn[128];
    __shared__ float cn[128];
    {
        const int idx  = tid & 127;
        const int base = (tid < 128) ? rowBase : colBase;
        const float4* p = (const float4*)(X + (size_t)(base + idx) * DD);
        float acc = 0.0f;
        #pragma unroll
        for (int i = 0; i < 16; ++i) {
            float4 v = p[i];
            acc += v.x * v.x + v.y * v.y + v.z * v.z + v.w * v.w;
        }
        if (tid < 128) rn[idx] = acc;
        else           cn[idx] = acc;
    }
    __syncthreads();

    f32x4 acc[4][4];
    #pragma unroll
    for (int m = 0; m < 4; ++m)
        #pragma unroll
        for (int n = 0; n < 4; ++n)
            acc[m][n] = (f32x4){0.f, 0.f, 0.f, 0.f};

    const int fr = lane & 15;
    const int kg = lane >> 4;

    #pragma unroll
    for (int kk = 0; kk < DD; kk += 32) {
        bf16x8 a[4], b[4];
        #pragma unroll
        for (int m = 0; m < 4; ++m) {
            const float* p = X + (size_t)(rowBase + wr * 64 + m * 16 + fr) * DD + kk + kg * 8;
            float4 lo = *(const float4*)p;
            float4 hi = *(const float4*)(p + 4);
            bf16x8 t;
            t[0] = (short)f2bf(lo.x); t[1] = (short)f2bf(lo.y);
            t[2] = (short)f2bf(lo.z); t[3] = (short)f2bf(lo.w);
            t[4] = (short)f2bf(hi.x); t[5] = (short)f2bf(hi.y);
            t[6] = (short)f2bf(hi.z); t[7] = (short)f2bf(hi.w);
            a[m] = t;
        }
        #pragma unroll
        for (int n = 0; n < 4; ++n) {
            const float* p = X + (size_t)(colBase + wc * 64 + n * 16 + fr) * DD + kk + kg * 8;
            float4 lo = *(const float4*)p;
            float4 hi = *(const float4*)(p + 4);
            bf16x8 t;
            t[0] = (short)f2bf(lo.x); t[1] = (short)f2bf(lo.y);
            t[2] = (short)f2bf(lo.z); t[3] = (short)f2bf(lo.w);
            t[4] = (short)f2bf(hi.x); t[5] = (short)f2bf(hi.y);
            t[6] = (short)f2bf(hi.z); t[7] = (short)f2bf(hi.w);
            b[n] = t;
        }
        #pragma unroll
        for (int m = 0; m < 4; ++m)
            #pragma unroll
            for (int n = 0; n < 4; ++n)
                acc[m][n] = __builtin_amdgcn_mfma_f32_16x16x32_bf16(a[m], b[n], acc[m][n], 0, 0, 0);
    }

    #pragma unroll
    for (int m = 0; m < 4; ++m) {
        #pragma unroll
        for (int n = 0; n < 4; ++n) {
            #pragma unroll
            for (int r = 0; r < 4; ++r) {
                const int row_l = wr * 64 + m * 16 + kg * 4 + r;
                const int col_l = wc * 64 + n * 16 + fr;
                const float g  = acc[m][n][r];
                float sq = rn[row_l] + cn[col_l] - 2.0f * g;
                sq = fmaxf(sq, 0.0f);
                float dv = sqrtf(sq);
                const int grow = rowBase + row_l;
                const int gcol = colBase + col_l;
                if (grow == gcol) dv = 0.0f;
                out[(size_t)grow * NN + gcol] = dv;
            }
        }
    }
}

extern "C" void kernel_launch(void* const* d_in, const int* in_sizes, int n_in,
                              void* d_out, int out_size, void* d_ws, size_t ws_size,
                              hipStream_t stream) {
    const float* X = (const float*)d_in[0];
    float* out = (float*)d_out;

    const size_t xb_bytes   = (size_t)NN * DD * sizeof(unsigned short); // 1 MiB
    const size_t norm_bytes = (size_t)NN * sizeof(float);               // 32 KiB

    if (ws_size >= xb_bytes + norm_bytes) {
        unsigned short* Xb = (unsigned short*)d_ws;
        float* norms = (float*)((char*)d_ws + xb_bytes);
        rips_setup<<<dim3(NN * 8 / 256, 1, 1), dim3(256, 1, 1), 0, stream>>>(X, Xb, norms);
        rips_stripe<<<dim3(NN / 16, 1, 1), dim3(512, 1, 1), 0, stream>>>(Xb, norms, out);
    } else {
        dim3 grid(NN / 128, NN / 128, 1);
        rips_fallback<<<grid, dim3(256, 1, 1), 0, stream>>>(X, out);
    }
}

// Round 9
// 66.376 us; speedup vs baseline: 1.3177x; 1.3177x over previous
//
#include <hip/hip_runtime.h>

#define NN 8192
#define DD 64

typedef short bf16x8 __attribute__((ext_vector_type(8)));
typedef float f32x4 __attribute__((ext_vector_type(4)));

__device__ __forceinline__ unsigned short f2bf(float f) {
    unsigned int u = __float_as_uint(f);
    unsigned int r = (u + 0x7FFFu + ((u >> 16) & 1u)) >> 16;
    return (unsigned short)r;
}

__device__ __forceinline__ float fsqrt(float x) {
#if __has_builtin(__builtin_amdgcn_sqrtf)
    return __builtin_amdgcn_sqrtf(x);
#else
    return sqrtf(x);
#endif
}

// ---- Setup: X fp32 -> bf16 (RNE) into ws, plus per-row squared norms ----
__global__ __launch_bounds__(256) void rips_setup(const float* __restrict__ X,
                                                  unsigned short* __restrict__ Xb,
                                                  float* __restrict__ norms) {
    const int t   = blockIdx.x * 256 + threadIdx.x;
    const int row = t >> 3;
    const int j   = t & 7;
    const float* p = X + (size_t)row * DD + j * 8;
    float4 lo = *(const float4*)p;
    float4 hi = *(const float4*)(p + 4);

    bf16x8 v;
    v[0] = (short)f2bf(lo.x); v[1] = (short)f2bf(lo.y);
    v[2] = (short)f2bf(lo.z); v[3] = (short)f2bf(lo.w);
    v[4] = (short)f2bf(hi.x); v[5] = (short)f2bf(hi.y);
    v[6] = (short)f2bf(hi.z); v[7] = (short)f2bf(hi.w);
    *(bf16x8*)(Xb + (size_t)row * DD + j * 8) = v;

    float acc = lo.x*lo.x + lo.y*lo.y + lo.z*lo.z + lo.w*lo.w
              + hi.x*hi.x + hi.y*hi.y + hi.z*hi.z + hi.w*hi.w;
    acc += __shfl_xor(acc, 1);
    acc += __shfl_xor(acc, 2);
    acc += __shfl_xor(acc, 4);
    if (j == 0) norms[row] = acc;
}

// ---- Main (H5: occupancy): 64x128 tile per block, 4 waves of 32x64 each.
// acc[2][4]=32 VGPR, target <=64 total via __launch_bounds__(256,8) ->
// 8 waves/SIMD = 32 waves/CU (2x R6) = 2x wave-level outstanding-store
// concurrency. Store geometry identical to R6 (best so far): per-wave LDS
// stage, 4 rows x 256B contiguous per store instruction.
__global__ __launch_bounds__(256, 8) void rips_main(const unsigned short* __restrict__ Xb,
                                                    const float* __restrict__ norms,
                                                    float* __restrict__ out) {
    const int bid = blockIdx.x;
    const int rowBase = (bid >> 6) * 64;    // 128 row-tiles
    const int colBase = (bid & 63) * 128;   // 64 col-tiles

    const int tid  = threadIdx.x;
    const int lane = tid & 63;
    const int w    = tid >> 6;
    const int wr   = w >> 1;                // row band 0..1 (32 rows)
    const int wc   = w & 1;                 // col band 0..1 (64 cols)

    __shared__ float rn[64];
    __shared__ float cn[128];
    __shared__ float stage[4][16 * 68];     // per-wave 16x64 slice, stride 68

    if (tid < 64) rn[tid] = norms[rowBase + tid];
    else if (tid < 192) cn[tid - 64] = norms[colBase + tid - 64];
    __syncthreads();

    const int fr = lane & 15;
    const int kg = lane >> 4;

    f32x4 acc[2][4];
    #pragma unroll
    for (int m = 0; m < 2; ++m)
        #pragma unroll
        for (int n = 0; n < 4; ++n)
            acc[m][n] = (f32x4){0.f, 0.f, 0.f, 0.f};

    #pragma unroll
    for (int kk = 0; kk < DD; kk += 32) {
        bf16x8 a[4], b[2];
        #pragma unroll
        for (int n = 0; n < 4; ++n)
            a[n] = *(const bf16x8*)(Xb + (size_t)(colBase + wc * 64 + n * 16 + fr) * DD + kk + kg * 8);
        #pragma unroll
        for (int m = 0; m < 2; ++m)
            b[m] = *(const bf16x8*)(Xb + (size_t)(rowBase + wr * 32 + m * 16 + fr) * DD + kk + kg * 8);
        #pragma unroll
        for (int m = 0; m < 2; ++m)
            #pragma unroll
            for (int n = 0; n < 4; ++n)
                acc[m][n] = __builtin_amdgcn_mfma_f32_16x16x32_bf16(a[n], b[m], acc[m][n], 0, 0, 0);
    }

    // Epilogue: per 16-row m-slice, compute -> LDS stage -> 4x(4rows x 256B).
    float* st = stage[w];
    const int lr = lane >> 4;   // 0..3 store row-in-group
    const int lc = lane & 15;   // 0..15 store 16B col group

    #pragma unroll
    for (int m = 0; m < 2; ++m) {
        const int row_l = wr * 32 + m * 16 + fr;
        const int grow  = rowBase + row_l;
        const float rnv = rn[row_l];
        #pragma unroll
        for (int n = 0; n < 4; ++n) {
            const int col_l = wc * 64 + n * 16 + kg * 4;
            const int gcol0 = colBase + col_l;
            const float4 cnv = *(const float4*)&cn[col_l];
            f32x4 o;
            o[0] = fsqrt(fmaxf(rnv + cnv.x - 2.0f * acc[m][n][0], 0.0f));
            o[1] = fsqrt(fmaxf(rnv + cnv.y - 2.0f * acc[m][n][1], 0.0f));
            o[2] = fsqrt(fmaxf(rnv + cnv.z - 2.0f * acc[m][n][2], 0.0f));
            o[3] = fsqrt(fmaxf(rnv + cnv.w - 2.0f * acc[m][n][3], 0.0f));
            if (grow == gcol0 + 0) o[0] = 0.0f;
            if (grow == gcol0 + 1) o[1] = 0.0f;
            if (grow == gcol0 + 2) o[2] = 0.0f;
            if (grow == gcol0 + 3) o[3] = 0.0f;
            *(f32x4*)&st[fr * 68 + n * 16 + kg * 4] = o;
        }
        #pragma unroll
        for (int t = 0; t < 4; ++t) {
            const int R = t * 4 + lr;
            f32x4 v = *(const f32x4*)&st[R * 68 + lc * 4];
            const int srow = rowBase + wr * 32 + m * 16 + R;
            const int scol = colBase + wc * 64 + lc * 4;
            *(f32x4*)(out + (size_t)srow * NN + scol) = v;
        }
    }
}

// ---- Fallback (R1 kernel): used only if ws_size is too small ----
__global__ __launch_bounds__(256) void rips_fallback(const float* __restrict__ X,
                                                     float* __restrict__ out) {
    const int rowBase = blockIdx.y * 128;
    const int colBase = blockIdx.x * 128;
    const int tid  = threadIdx.x;
    const int lane = tid & 63;
    const int w    = tid >> 6;
    const int wr   = w >> 1;
    const int wc   = w & 1;

    __shared__ float rn[128];
    __shared__ float cn[128];
    {
        const int idx  = tid & 127;
        const int base = (tid < 128) ? rowBase : colBase;
        const float4* p = (const float4*)(X + (size_t)(base + idx) * DD);
        float acc = 0.0f;
        #pragma unroll
        for (int i = 0; i < 16; ++i) {
            float4 v = p[i];
            acc += v.x * v.x + v.y * v.y + v.z * v.z + v.w * v.w;
        }
        if (tid < 128) rn[idx] = acc;
        else           cn[idx] = acc;
    }
    __syncthreads();

    f32x4 acc[4][4];
    #pragma unroll
    for (int m = 0; m < 4; ++m)
        #pragma unroll
        for (int n = 0; n < 4; ++n)
            acc[m][n] = (f32x4){0.f, 0.f, 0.f, 0.f};

    const int fr = lane & 15;
    const int kg = lane >> 4;

    #pragma unroll
    for (int kk = 0; kk < DD; kk += 32) {
        bf16x8 a[4], b[4];
        #pragma unroll
        for (int m = 0; m < 4; ++m) {
            const float* p = X + (size_t)(rowBase + wr * 64 + m * 16 + fr) * DD + kk + kg * 8;
            float4 lo = *(const float4*)p;
            float4 hi = *(const float4*)(p + 4);
            bf16x8 t;
            t[0] = (short)f2bf(lo.x); t[1] = (short)f2bf(lo.y);
            t[2] = (short)f2bf(lo.z); t[3] = (short)f2bf(lo.w);
            t[4] = (short)f2bf(hi.x); t[5] = (short)f2bf(hi.y);
            t[6] = (short)f2bf(hi.z); t[7] = (short)f2bf(hi.w);
            a[m] = t;
        }
        #pragma unroll
        for (int n = 0; n < 4; ++n) {
            const float* p = X + (size_t)(colBase + wc * 64 + n * 16 + fr) * DD + kk + kg * 8;
            float4 lo = *(const float4*)p;
            float4 hi = *(const float4*)(p + 4);
            bf16x8 t;
            t[0] = (short)f2bf(lo.x); t[1] = (short)f2bf(lo.y);
            t[2] = (short)f2bf(lo.z); t[3] = (short)f2bf(lo.w);
            t[4] = (short)f2bf(hi.x); t[5] = (short)f2bf(hi.y);
            t[6] = (short)f2bf(hi.z); t[7] = (short)f2bf(hi.w);
            b[n] = t;
        }
        #pragma unroll
        for (int m = 0; m < 4; ++m)
            #pragma unroll
            for (int n = 0; n < 4; ++n)
                acc[m][n] = __builtin_amdgcn_mfma_f32_16x16x32_bf16(a[m], b[n], acc[m][n], 0, 0, 0);
    }

    #pragma unroll
    for (int m = 0; m < 4; ++m) {
        #pragma unroll
        for (int n = 0; n < 4; ++n) {
            #pragma unroll
            for (int r = 0; r < 4; ++r) {
                const int row_l = wr * 64 + m * 16 + kg * 4 + r;
                const int col_l = wc * 64 + n * 16 + fr;
                const float g  = acc[m][n][r];
                float sq = rn[row_l] + cn[col_l] - 2.0f * g;
                sq = fmaxf(sq, 0.0f);
                float dv = sqrtf(sq);
                const int grow = rowBase + row_l;
                const int gcol = colBase + col_l;
                if (grow == gcol) dv = 0.0f;
                out[(size_t)grow * NN + gcol] = dv;
            }
        }
    }
}

extern "C" void kernel_launch(void* const* d_in, const int* in_sizes, int n_in,
                              void* d_out, int out_size, void* d_ws, size_t ws_size,
                              hipStream_t stream) {
    const float* X = (const float*)d_in[0];
    float* out = (float*)d_out;

    const size_t xb_bytes   = (size_t)NN * DD * sizeof(unsigned short); // 1 MiB
    const size_t norm_bytes = (size_t)NN * sizeof(float);               // 32 KiB

    if (ws_size >= xb_bytes + norm_bytes) {
        unsigned short* Xb = (unsigned short*)d_ws;
        float* norms = (float*)((char*)d_ws + xb_bytes);
        rips_setup<<<dim3(NN * 8 / 256, 1, 1), dim3(256, 1, 1), 0, stream>>>(X, Xb, norms);
        rips_main<<<dim3((NN / 64) * (NN / 128), 1, 1), dim3(256, 1, 1), 0, stream>>>(Xb, norms, out);
    } else {
        dim3 grid(NN / 128, NN / 128, 1);
        rips_fallback<<<grid, dim3(256, 1, 1), 0, stream>>>(X, out);
    }
}

// Round 10
// 65.867 us; speedup vs baseline: 1.3279x; 1.0077x over previous
//
#include <hip/hip_runtime.h>

#define NN 8192
#define DD 64

typedef short bf16x8 __attribute__((ext_vector_type(8)));
typedef float f32x4 __attribute__((ext_vector_type(4)));

__device__ __forceinline__ unsigned short f2bf(float f) {
    unsigned int u = __float_as_uint(f);
    unsigned int r = (u + 0x7FFFu + ((u >> 16) & 1u)) >> 16;
    return (unsigned short)r;
}

__device__ __forceinline__ float fsqrt(float x) {
#if __has_builtin(__builtin_amdgcn_sqrtf)
    return __builtin_amdgcn_sqrtf(x);
#else
    return sqrtf(x);
#endif
}

// ---- Setup: X fp32 -> bf16 (RNE) into ws, plus per-row squared norms ----
__global__ __launch_bounds__(256) void rips_setup(const float* __restrict__ X,
                                                  unsigned short* __restrict__ Xb,
                                                  float* __restrict__ norms) {
    const int t   = blockIdx.x * 256 + threadIdx.x;
    const int row = t >> 3;
    const int j   = t & 7;
    const float* p = X + (size_t)row * DD + j * 8;
    float4 lo = *(const float4*)p;
    float4 hi = *(const float4*)(p + 4);

    bf16x8 v;
    v[0] = (short)f2bf(lo.x); v[1] = (short)f2bf(lo.y);
    v[2] = (short)f2bf(lo.z); v[3] = (short)f2bf(lo.w);
    v[4] = (short)f2bf(hi.x); v[5] = (short)f2bf(hi.y);
    v[6] = (short)f2bf(hi.z); v[7] = (short)f2bf(hi.w);
    *(bf16x8*)(Xb + (size_t)row * DD + j * 8) = v;

    float acc = lo.x*lo.x + lo.y*lo.y + lo.z*lo.z + lo.w*lo.w
              + hi.x*hi.x + hi.y*hi.y + hi.z*hi.z + hi.w*hi.w;
    acc += __shfl_xor(acc, 1);
    acc += __shfl_xor(acc, 2);
    acc += __shfl_xor(acc, 4);
    if (j == 0) norms[row] = acc;
}

// ---- Main (H5 clean test): 64x128 tile, 4 waves of 32x64, acc[2][4]=32 VGPR.
// __launch_bounds__(256,6) -> VGPR cap 85 (trimmed live set ~80, NO spills,
// unlike R9's forced 64) -> 6 waves/SIMD = 24 waves/CU (1.5x R6's ~16).
// Store geometry identical to R6 (best): per-wave LDS stage, 4 rows x 256B
// contiguous per store instruction.
__global__ __launch_bounds__(256, 6) void rips_main(const unsigned short* __restrict__ Xb,
                                                    const float* __restrict__ norms,
                                                    float* __restrict__ out) {
    const int bid = blockIdx.x;
    const int rowBase = (bid >> 6) * 64;    // 128 row-tiles
    const int colBase = (bid & 63) * 128;   // 64 col-tiles

    const int tid  = threadIdx.x;
    const int lane = tid & 63;
    const int w    = tid >> 6;
    const int wr   = w >> 1;                // row band 0..1 (32 rows)
    const int wc   = w & 1;                 // col band 0..1 (64 cols)

    __shared__ float rn[64];
    __shared__ float cn[128];
    __shared__ float stage[4][16 * 68];     // per-wave 16x64 slice, stride 68

    if (tid < 64) rn[tid] = norms[rowBase + tid];
    else if (tid < 192) cn[tid - 64] = norms[colBase + tid - 64];
    __syncthreads();

    const int fr = lane & 15;
    const int kg = lane >> 4;

    f32x4 acc[2][4];
    #pragma unroll
    for (int m = 0; m < 2; ++m)
        #pragma unroll
        for (int n = 0; n < 4; ++n)
            acc[m][n] = (f32x4){0.f, 0.f, 0.f, 0.f};

    // K-loop with interleaved fragment loads to minimize live registers:
    // live ~= acc(32) + b0,b1(16) + a(8) + addressing.
    #pragma unroll
    for (int kk = 0; kk < DD; kk += 32) {
        const bf16x8 b0 = *(const bf16x8*)(Xb + (size_t)(rowBase + wr * 32 + 0  + fr) * DD + kk + kg * 8);
        const bf16x8 b1 = *(const bf16x8*)(Xb + (size_t)(rowBase + wr * 32 + 16 + fr) * DD + kk + kg * 8);
        #pragma unroll
        for (int n = 0; n < 4; ++n) {
            const bf16x8 a = *(const bf16x8*)(Xb + (size_t)(colBase + wc * 64 + n * 16 + fr) * DD + kk + kg * 8);
            acc[0][n] = __builtin_amdgcn_mfma_f32_16x16x32_bf16(a, b0, acc[0][n], 0, 0, 0);
            acc[1][n] = __builtin_amdgcn_mfma_f32_16x16x32_bf16(a, b1, acc[1][n], 0, 0, 0);
        }
    }

    // Epilogue: per 16-row m-slice, compute -> LDS stage -> 4x(4rows x 256B).
    float* st = stage[w];
    const int lr = lane >> 4;   // 0..3 store row-in-group
    const int lc = lane & 15;   // 0..15 store 16B col group

    #pragma unroll
    for (int m = 0; m < 2; ++m) {
        const int row_l = wr * 32 + m * 16 + fr;
        const int grow  = rowBase + row_l;
        const float rnv = rn[row_l];
        #pragma unroll
        for (int n = 0; n < 4; ++n) {
            const int col_l = wc * 64 + n * 16 + kg * 4;
            const int gcol0 = colBase + col_l;
            const float4 cnv = *(const float4*)&cn[col_l];
            f32x4 o;
            o[0] = fsqrt(fmaxf(rnv + cnv.x - 2.0f * acc[m][n][0], 0.0f));
            o[1] = fsqrt(fmaxf(rnv + cnv.y - 2.0f * acc[m][n][1], 0.0f));
            o[2] = fsqrt(fmaxf(rnv + cnv.z - 2.0f * acc[m][n][2], 0.0f));
            o[3] = fsqrt(fmaxf(rnv + cnv.w - 2.0f * acc[m][n][3], 0.0f));
            if (grow == gcol0 + 0) o[0] = 0.0f;
            if (grow == gcol0 + 1) o[1] = 0.0f;
            if (grow == gcol0 + 2) o[2] = 0.0f;
            if (grow == gcol0 + 3) o[3] = 0.0f;
            *(f32x4*)&st[fr * 68 + n * 16 + kg * 4] = o;
        }
        #pragma unroll
        for (int t = 0; t < 4; ++t) {
            const int R = t * 4 + lr;
            f32x4 v = *(const f32x4*)&st[R * 68 + lc * 4];
            const int srow = rowBase + wr * 32 + m * 16 + R;
            const int scol = colBase + wc * 64 + lc * 4;
            *(f32x4*)(out + (size_t)srow * NN + scol) = v;
        }
    }
}

// ---- Fallback (R1 kernel): used only if ws_size is too small ----
__global__ __launch_bounds__(256) void rips_fallback(const float* __restrict__ X,
                                                     float* __restrict__ out) {
    const int rowBase = blockIdx.y * 128;
    const int colBase = blockIdx.x * 128;
    const int tid  = threadIdx.x;
    const int lane = tid & 63;
    const int w    = tid >> 6;
    const int wr   = w >> 1;
    const int wc   = w & 1;

    __shared__ float rn[128];
    __shared__ float cn[128];
    {
        const int idx  = tid & 127;
        const int base = (tid < 128) ? rowBase : colBase;
        const float4* p = (const float4*)(X + (size_t)(base + idx) * DD);
        float acc = 0.0f;
        #pragma unroll
        for (int i = 0; i < 16; ++i) {
            float4 v = p[i];
            acc += v.x * v.x + v.y * v.y + v.z * v.z + v.w * v.w;
        }
        if (tid < 128) rn[idx] = acc;
        else           cn[idx] = acc;
    }
    __syncthreads();

    f32x4 acc[4][4];
    #pragma unroll
    for (int m = 0; m < 4; ++m)
        #pragma unroll
        for (int n = 0; n < 4; ++n)
            acc[m][n] = (f32x4){0.f, 0.f, 0.f, 0.f};

    const int fr = lane & 15;
    const int kg = lane >> 4;

    #pragma unroll
    for (int kk = 0; kk < DD; kk += 32) {
        bf16x8 a[4], b[4];
        #pragma unroll
        for (int m = 0; m < 4; ++m) {
            const float* p = X + (size_t)(rowBase + wr * 64 + m * 16 + fr) * DD + kk + kg * 8;
            float4 lo = *(const float4*)p;
            float4 hi = *(const float4*)(p + 4);
            bf16x8 t;
            t[0] = (short)f2bf(lo.x); t[1] = (short)f2bf(lo.y);
            t[2] = (short)f2bf(lo.z); t[3] = (short)f2bf(lo.w);
            t[4] = (short)f2bf(hi.x); t[5] = (short)f2bf(hi.y);
            t[6] = (short)f2bf(hi.z); t[7] = (short)f2bf(hi.w);
            a[m] = t;
        }
        #pragma unroll
        for (int n = 0; n < 4; ++n) {
            const float* p = X + (size_t)(colBase + wc * 64 + n * 16 + fr) * DD + kk + kg * 8;
            float4 lo = *(const float4*)p;
            float4 hi = *(const float4*)(p + 4);
            bf16x8 t;
            t[0] = (short)f2bf(lo.x); t[1] = (short)f2bf(lo.y);
            t[2] = (short)f2bf(lo.z); t[3] = (short)f2bf(lo.w);
            t[4] = (short)f2bf(hi.x); t[5] = (short)f2bf(hi.y);
            t[6] = (short)f2bf(hi.z); t[7] = (short)f2bf(hi.w);
            b[n] = t;
        }
        #pragma unroll
        for (int m = 0; m < 4; ++m)
            #pragma unroll
            for (int n = 0; n < 4; ++n)
                acc[m][n] = __builtin_amdgcn_mfma_f32_16x16x32_bf16(a[m], b[n], acc[m][n], 0, 0, 0);
    }

    #pragma unroll
    for (int m = 0; m < 4; ++m) {
        #pragma unroll
        for (int n = 0; n < 4; ++n) {
            #pragma unroll
            for (int r = 0; r < 4; ++r) {
                const int row_l = wr * 64 + m * 16 + kg * 4 + r;
                const int col_l = wc * 64 + n * 16 + fr;
                const float g  = acc[m][n][r];
                float sq = rn[row_l] + cn[col_l] - 2.0f * g;
                sq = fmaxf(sq, 0.0f);
                float dv = sqrtf(sq);
                const int grow = rowBase + row_l;
                const int gcol = colBase + col_l;
                if (grow == gcol) dv = 0.0f;
                out[(size_t)grow * NN + gcol] = dv;
            }
        }
    }
}

extern "C" void kernel_launch(void* const* d_in, const int* in_sizes, int n_in,
                              void* d_out, int out_size, void* d_ws, size_t ws_size,
                              hipStream_t stream) {
    const float* X = (const float*)d_in[0];
    float* out = (float*)d_out;

    const size_t xb_bytes   = (size_t)NN * DD * sizeof(unsigned short); // 1 MiB
    const size_t norm_bytes = (size_t)NN * sizeof(float);               // 32 KiB

    if (ws_size >= xb_bytes + norm_bytes) {
        unsigned short* Xb = (unsigned short*)d_ws;
        float* norms = (float*)((char*)d_ws + xb_bytes);
        rips_setup<<<dim3(NN * 8 / 256, 1, 1), dim3(256, 1, 1), 0, stream>>>(X, Xb, norms);
        rips_main<<<dim3((NN / 64) * (NN / 128), 1, 1), dim3(256, 1, 1), 0, stream>>>(Xb, norms, out);
    } else {
        dim3 grid(NN / 128, NN / 128, 1);
        rips_fallback<<<grid, dim3(256, 1, 1), 0, stream>>>(X, out);
    }
}